// Round 1
// baseline (918.367 us; speedup 1.0000x reference)
//
#include <hip/hip_runtime.h>
#include <stdint.h>

// Problem constants (from reference): x(N,C,IN) fp32, W(C,OUT,IN) fp32, b(C,OUT) fp32
// out[n,c,o] = sum_i x[n,c,i]*W[c,o,i] + b[c,o]
#define N_TOT 32768
#define C_CH  8
#define K_IN  512
#define OUT_F 512

#define BM 128   // rows of n per block
#define BN 128   // cols of o per block
#define BK 64    // k-chunk per staging step
#define NSTEPS (K_IN / BK)  // 8
#define LDA 72   // LDS row stride in shorts (64 + 8 pad -> 144 B, breaks bank aliasing to 2-way)

typedef __attribute__((ext_vector_type(4))) float    f32x4;
typedef __attribute__((ext_vector_type(8))) short    s16x8;
typedef __attribute__((ext_vector_type(4))) uint32_t u32x4;

// 4 fp32 -> 4 bf16 (round-to-nearest via +0x8000 bias) packed with v_perm_b32, 8-B LDS write.
__device__ __forceinline__ void cvt_store8(short* dst, u32x4 v) {
  uint32_t r0 = v.x + 0x8000u;
  uint32_t r1 = v.y + 0x8000u;
  uint32_t r2 = v.z + 0x8000u;
  uint32_t r3 = v.w + 0x8000u;
  uint32_t p0 = __builtin_amdgcn_perm(r1, r0, 0x07060302u); // [bf(f0), bf(f1)]
  uint32_t p1 = __builtin_amdgcn_perm(r3, r2, 0x07060302u); // [bf(f2), bf(f3)]
  uint2 pk; pk.x = p0; pk.y = p1;
  *(uint2*)dst = pk;
}

extern "C" __global__ void __launch_bounds__(256, 2)
mcl_gemm(const float* __restrict__ xg, const float* __restrict__ wg,
         const float* __restrict__ bg, float* __restrict__ og) {
  __shared__ short lA[BM * LDA];
  __shared__ short lB[BN * LDA];

  // bid = ntile*32 + otile*8 + c : x-sharing siblings (same ntile,c; otile 0..3)
  // differ by 8 -> same XCD under %8 round-robin -> L2 reuse of the x chunk.
  const int bid   = blockIdx.x;
  const int c     = bid & 7;
  const int otile = (bid >> 3) & 3;
  const int ntile = bid >> 5;

  const int tid  = threadIdx.x;
  const int lane = tid & 63;
  const int wave = tid >> 6;
  const int wm   = wave & 1;   // wave row (n dim): 0..1
  const int wn   = wave >> 1;  // wave col (o dim): 0..1

  const int row0 = ntile * BM; // base n
  const int col0 = otile * BN; // base o

  // ---- staging addressing: thread t loads 16 B (4 fp32) at row sr, float-col scf.
  // lanes 0..15 cover one 256-B row contiguously -> perfect coalescing.
  const int sr  = tid >> 4;        // 0..15, +16 per staging iter (8 iters -> 128 rows)
  const int scf = (tid & 15) * 4;  // 0..60
  const float* ap = xg + ((size_t)(row0 + sr) * C_CH + c) * K_IN + scf;
  const float* bp = wg + ((size_t)c * OUT_F + (col0 + sr)) * K_IN + scf;
  short* aw = lA + sr * LDA + scf;
  short* bw = lB + sr * LDA + scf;

  const size_t a_row_stride = (size_t)16 * C_CH * K_IN; // 16 n-rows
  const size_t b_row_stride = (size_t)16 * K_IN;        // 16 o-rows

  // ---- prologue: load k-chunk 0 into registers (fire-and-forget prefetch style)
  u32x4 areg[8], breg[8];
#pragma unroll
  for (int i = 0; i < 8; ++i) areg[i] = *(const u32x4*)(ap + (size_t)i * a_row_stride);
#pragma unroll
  for (int i = 0; i < 8; ++i) breg[i] = *(const u32x4*)(bp + (size_t)i * b_row_stride);

  f32x4 acc[4][4];
#pragma unroll
  for (int mi = 0; mi < 4; ++mi)
#pragma unroll
    for (int ni = 0; ni < 4; ++ni)
#pragma unroll
      for (int e = 0; e < 4; ++e) acc[mi][ni][e] = 0.0f;

  const int fl   = lane & 15;
  const int quad = lane >> 4;
  // fragment read bases: row = (wave 64-block + tile*16 + fl), k-offset = quad*8
  const short* arp = lA + (wm * 64 + fl) * LDA + quad * 8;
  const short* brp = lB + (wn * 64 + fl) * LDA + quad * 8;

  for (int step = 0; step < NSTEPS; ++step) {
    // convert + write current chunk to LDS (vmcnt wait happens here, after prior compute)
#pragma unroll
    for (int i = 0; i < 8; ++i) cvt_store8(aw + i * 16 * LDA, areg[i]);
#pragma unroll
    for (int i = 0; i < 8; ++i) cvt_store8(bw + i * 16 * LDA, breg[i]);
    __syncthreads();

    // prefetch next chunk NOW — loads stay in flight through the MFMA phase
    if (step + 1 < NSTEPS) {
      const float* ap2 = ap + (step + 1) * BK;
      const float* bp2 = bp + (step + 1) * BK;
#pragma unroll
      for (int i = 0; i < 8; ++i) areg[i] = *(const u32x4*)(ap2 + (size_t)i * a_row_stride);
#pragma unroll
      for (int i = 0; i < 8; ++i) breg[i] = *(const u32x4*)(bp2 + (size_t)i * b_row_stride);
    }

    // compute: 2 k-substeps x 16 MFMA
#pragma unroll
    for (int kk = 0; kk < BK; kk += 32) {
      s16x8 af[4], bf[4];
#pragma unroll
      for (int mi = 0; mi < 4; ++mi)
        af[mi] = *(const s16x8*)(arp + mi * 16 * LDA + kk);
#pragma unroll
      for (int ni = 0; ni < 4; ++ni)
        bf[ni] = *(const s16x8*)(brp + ni * 16 * LDA + kk);
#pragma unroll
      for (int mi = 0; mi < 4; ++mi)
#pragma unroll
        for (int ni = 0; ni < 4; ++ni)
          acc[mi][ni] = __builtin_amdgcn_mfma_f32_16x16x32_bf16(af[mi], bf[ni], acc[mi][ni], 0, 0, 0);
    }
    __syncthreads(); // protect LDS before next overwrite
  }

  // ---- epilogue: C/D layout col = lane&15 (o), row = quad*4 + reg (n)
  float bias[4];
#pragma unroll
  for (int ni = 0; ni < 4; ++ni)
    bias[ni] = bg[c * OUT_F + col0 + wn * 64 + ni * 16 + fl];

#pragma unroll
  for (int mi = 0; mi < 4; ++mi) {
#pragma unroll
    for (int r = 0; r < 4; ++r) {
      const int n = row0 + wm * 64 + mi * 16 + quad * 4 + r;
      float* orow = og + ((size_t)n * C_CH + c) * OUT_F + col0 + wn * 64 + fl;
#pragma unroll
      for (int ni = 0; ni < 4; ++ni)
        __builtin_nontemporal_store(acc[mi][ni][r] + bias[ni], orow + ni * 16);
    }
  }
}

extern "C" void kernel_launch(void* const* d_in, const int* in_sizes, int n_in,
                              void* d_out, int out_size, void* d_ws, size_t ws_size,
                              hipStream_t stream) {
  const float* x = (const float*)d_in[0];
  const float* W = (const float*)d_in[1];
  const float* b = (const float*)d_in[2];
  float* out = (float*)d_out;
  // grid = (N/BM) * (OUT/BN) * C = 256 * 4 * 8 = 8192 blocks
  dim3 grid((N_TOT / BM) * (OUT_F / BN) * C_CH);
  mcl_gemm<<<grid, dim3(256), 0, stream>>>(x, W, b, out);
}